// Round 6
// baseline (410.451 us; speedup 1.0000x reference)
//
#include <hip/hip_runtime.h>
#include <math.h>

#define Bn 4
#define Cn 96
#define Hn 128
#define Wn 128
#define Ln (Hn*Wn)      // 16384
#define Kn 2
#define Rn 6
#define SC 16           // scan chunk length
#define NCH (Ln/SC)     // 1024 chunks per (b,k)

__device__ __forceinline__ float siluf(float x) { return x / (1.f + __expf(-x)); }
__device__ __forceinline__ float softplusf(float x) {
    return fmaxf(x, 0.f) + log1pf(__expf(-fabsf(x)));
}

// ---------------------------------------------------------------------------
// Kernel A: in_proj GEMM. x (B,C,L) -> xc (B,L,C), zs=silu(z) (B,L,C).
// block = 256 thr, tile 64 pos x 192 out, thread = 4 pos x 12 out.
// Epilogue stages the output tile in LDS so all global stores are coalesced
// float4 (scalar lane-strided stores caused 4.6x HBM write amplification).
// ---------------------------------------------------------------------------
__global__ __launch_bounds__(256, 4) void k_inproj(
    const float* __restrict__ x, const float* __restrict__ ipw,
    float* __restrict__ xc, float* __restrict__ zs)
{
    __shared__ float smem[2048 + 6272];  // xls(32x64) + wls(32x196) = 33.3 KB
    float* xls = smem;                   // [k][p]
    float* wls = smem + 2048;            // [k][o] pad 196
    float* stage = smem;                 // reused after K loop: [p][c] pad 100

    const int t  = threadIdx.x;
    const int b  = blockIdx.x >> 8;
    const int l0 = (blockIdx.x & 255) << 6;
    const int tx = t & 15;
    const int ty = t >> 4;

    float acc[12][4];
#pragma unroll
    for (int i = 0; i < 12; ++i)
#pragma unroll
        for (int j = 0; j < 4; ++j) acc[i][j] = 0.f;

    const float* xbase = x + (size_t)b * Cn * Ln + l0;

    for (int k0 = 0; k0 < Cn; k0 += 32) {
        if (k0) __syncthreads();
        {
            int idx = t;
#pragma unroll
            for (int q = 0; q < 2; ++q, idx += 256) {
                int k = idx >> 4, p4 = idx & 15;
                *(float4*)&xls[k * 64 + p4 * 4] =
                    *(const float4*)&xbase[(size_t)(k0 + k) * Ln + p4 * 4];
            }
        }
        for (int idx = t; idx < 32 * 192; idx += 256) {
            int o = idx % 192, k = idx / 192;
            wls[k * 196 + o] = ipw[o * Cn + k0 + k];
        }
        __syncthreads();

#pragma unroll 4
        for (int kk = 0; kk < 32; ++kk) {
            float4 xv = *(const float4*)&xls[kk * 64 + tx * 4];
            const float* wrow = &wls[kk * 196 + ty * 12];
            float4 w0 = *(const float4*)&wrow[0];
            float4 w1 = *(const float4*)&wrow[4];
            float4 w2 = *(const float4*)&wrow[8];
            float wv[12] = {w0.x,w0.y,w0.z,w0.w,w1.x,w1.y,w1.z,w1.w,w2.x,w2.y,w2.z,w2.w};
            float xa[4]  = {xv.x, xv.y, xv.z, xv.w};
#pragma unroll
            for (int i = 0; i < 12; ++i)
#pragma unroll
                for (int j = 0; j < 4; ++j)
                    acc[i][j] = fmaf(wv[i], xa[j], acc[i][j]);
        }
    }

    __syncthreads();
    if (ty < 8) {
#pragma unroll
        for (int j = 0; j < 4; ++j)
#pragma unroll
            for (int i = 0; i < 12; ++i)
                stage[(tx * 4 + j) * 100 + ty * 12 + i] = acc[i][j];
    }
    __syncthreads();
    {
        float4* dst = (float4*)(xc + ((size_t)b * Ln + l0) * Cn);
        for (int idx = t; idx < 1536; idx += 256) {
            int p = idx / 24, c4 = idx % 24;
            dst[idx] = *(const float4*)&stage[p * 100 + c4 * 4];
        }
    }
    __syncthreads();
    if (ty >= 8) {
#pragma unroll
        for (int j = 0; j < 4; ++j)
#pragma unroll
            for (int i = 0; i < 12; ++i)
                stage[(tx * 4 + j) * 100 + (ty - 8) * 12 + i] = siluf(acc[i][j]);
    }
    __syncthreads();
    {
        float4* dst = (float4*)(zs + ((size_t)b * Ln + l0) * Cn);
        for (int idx = t; idx < 1536; idx += 256) {
            int p = idx / 24, c4 = idx % 24;
            dst[idx] = *(const float4*)&stage[p * 100 + c4 * 4];
        }
    }
}

// ---------------------------------------------------------------------------
// Kernel B: depthwise 3x3 conv (SAME) + bias + SiLU.  xc (B,L,C) -> u (B,L,C).
// ---------------------------------------------------------------------------
__global__ __launch_bounds__(256) void k_conv(
    const float* __restrict__ xc, const float* __restrict__ cw,
    const float* __restrict__ cb, float* __restrict__ u)
{
    const int e   = blockIdx.x * 256 + threadIdx.x;
    const int c   = e % Cn;
    const int pos = e / Cn;
    const int l   = pos % Ln;
    const int b   = pos / Ln;
    const int h   = l >> 7, w = l & 127;

    float acc = cb[c];
#pragma unroll
    for (int dh = -1; dh <= 1; ++dh) {
        int hh = h + dh;
        if (hh < 0 || hh >= Hn) continue;
#pragma unroll
        for (int dw = -1; dw <= 1; ++dw) {
            int ww = w + dw;
            if (ww < 0 || ww >= Wn) continue;
            acc = fmaf(cw[c*9 + (dh+1)*3 + (dw+1)],
                       xc[((size_t)b * Ln + (hh << 7) + ww) * Cn + c], acc);
        }
    }
    u[e] = siluf(acc);
}

// ---------------------------------------------------------------------------
// Kernel C: carry-only fused x_dbl + delta + local scan.
// 384 thr = 4 chunks x 96 channels, tile = 64 scan positions.
// Writes ONLY per-chunk carries (P,Q) — local products are recomputed in the
// epilogue kernel, eliminating the 200 MB yloc/cpb round trip.
// ---------------------------------------------------------------------------
__global__ __launch_bounds__(384) void k_fscan1(
    const float* __restrict__ u, const float* __restrict__ xpw,
    const float* __restrict__ dtw, const float* __restrict__ dtb,
    const float* __restrict__ Alogs,
    float* __restrict__ Pc, float* __restrict__ Qc)
{
    __shared__ float uls[64 * 100];  // [p][c] pad 100
    __shared__ float xd[64 * 8];     // [p][d]
    const int t   = threadIdx.x;
    const int seg = blockIdx.x & 255;
    const int k   = (blockIdx.x >> 8) & 1;
    const int b   = blockIdx.x >> 9;
    const int bk  = b * Kn + k;
    const int l0  = seg << 6;        // scan-position base (64 positions)

    if (k == 0) {
        const float* up = u + ((size_t)b * Ln + l0) * Cn;
        for (int idx = t; idx < 64 * Cn; idx += 384) {
            int p = idx / Cn, c = idx % Cn;
            uls[p * 100 + c] = up[idx];
        }
    } else {
        const float* up = u + ((size_t)b * Ln + (Ln - 64 - l0)) * Cn;
        for (int idx = t; idx < 64 * Cn; idx += 384) {
            int p = 63 - idx / Cn, c = idx % Cn;
            uls[p * 100 + c] = up[idx];
        }
    }
    __syncthreads();

    // x_dbl: 8 projections x 64 positions (only d=0..6 used for carries)
    for (int dp = t; dp < 512; dp += 384) {
        int d = dp & 7, p = dp >> 3;
        const float4* wr = (const float4*)(xpw + (k * 8 + d) * Cn);
        const float4* ur = (const float4*)&uls[p * 100];
        float acc = 0.f;
#pragma unroll
        for (int c4 = 0; c4 < 24; ++c4) {
            float4 w = wr[c4], v = ur[c4];
            acc = fmaf(w.x, v.x, acc); acc = fmaf(w.y, v.y, acc);
            acc = fmaf(w.z, v.z, acc); acc = fmaf(w.w, v.w, acc);
        }
        xd[p * 8 + d] = acc;
    }
    __syncthreads();

    const int c  = t % Cn;
    const int ci = t / Cn;           // chunk within tile: 0..3
    const int pbase = ci * SC;
    const float Av = -__expf(Alogs[k * Cn + c]);
    const float bias = dtb[k * Cn + c];
    float dtwr[Rn];
#pragma unroll
    for (int r = 0; r < Rn; ++r) dtwr[r] = dtw[(k * Cn + c) * Rn + r];

    float h = 0.f, cp = 1.f;
    for (int i = 0; i < SC; ++i) {
        const float* xr = &xd[(pbase + i) * 8];
        float de = bias;
#pragma unroll
        for (int r = 0; r < Rn; ++r) de = fmaf(dtwr[r], xr[r], de);
        de = softplusf(de);
        float dA = __expf(de * Av);
        float xv = uls[(pbase + i) * 100 + c];
        h = fmaf(dA, h, de * xv * xr[6]);
        cp *= dA;
    }
    const size_t cidx = ((size_t)bk * NCH + seg * 4 + ci) * Cn + c;
    Pc[cidx] = cp;
    Qc[cidx] = h;
}

// ---------------------------------------------------------------------------
// Kernel D: hierarchical carry scan. 768 series x 1024 chunks.
// Grid = 24 blocks (8 bk x 3 channel-slices of 32), block = 1024 thr (32c x 32g),
// group = 32 chunks: 32-step group carry, 32-step serial, 32-step replay.
// ---------------------------------------------------------------------------
__global__ __launch_bounds__(1024) void k_scan2(
    const float* __restrict__ Pc, const float* __restrict__ Qc,
    float* __restrict__ hinit)
{
    __shared__ float Pg[32][33], Qg[32][33], gini[32][33];
    const int bk    = blockIdx.x / 3;
    const int cbase = (blockIdx.x % 3) * 32;
    const int t = threadIdx.x;
    const int c = t & 31, g = t >> 5;

    const size_t base = ((size_t)bk * NCH + g * 32) * Cn + cbase + c;
    float P = 1.f, Q = 0.f;
    for (int j = 0; j < 32; ++j) {
        size_t idx = base + (size_t)j * Cn;
        float p_ = Pc[idx], q_ = Qc[idx];
        Q = fmaf(p_, Q, q_);
        P *= p_;
    }
    Pg[g][c] = P; Qg[g][c] = Q;
    __syncthreads();
    if (t < 32) {
        float h = 0.f;
        for (int gg = 0; gg < 32; ++gg) {
            gini[gg][t] = h;
            h = fmaf(Pg[gg][t], h, Qg[gg][t]);
        }
    }
    __syncthreads();
    float h = gini[g][c];
    for (int j = 0; j < 32; ++j) {
        size_t idx = base + (size_t)j * Cn;
        hinit[idx] = h;
        h = fmaf(Pc[idx], h, Qc[idx]);
    }
}

// ---------------------------------------------------------------------------
// Kernel E1: recompute + merge + LayerNorm + gate.
// Block = (b, 64-pos spatial tile), 768 thr = 2 dirs x 4 chunks x 96 channels.
// Stages u once; computes x_dbl for BOTH directions (k=1 scan positions map
// to the same spatial tile); re-runs the 8 chunk scans from their true hinit
// (carry folds into the recurrence — no correction term); merges directions
// in one LDS tile; LN over C; gate with silu(z); writes g.
// ---------------------------------------------------------------------------
__global__ __launch_bounds__(768) void k_scan3a(
    const float* __restrict__ u, const float* __restrict__ xpw,
    const float* __restrict__ dtw, const float* __restrict__ dtb,
    const float* __restrict__ Alogs, const float* __restrict__ hinit,
    const float* __restrict__ Ds, const float* __restrict__ onw,
    const float* __restrict__ onb, const float* __restrict__ zs,
    float* __restrict__ g)
{
    __shared__ float uls[64 * 100];  // 25.6 KB [p][c]
    __shared__ float xd[64 * 16];    //  4.1 KB [p][dd] dd=k*8+d
    __shared__ float yt[64 * 104];   // 26.6 KB [p][c]
    __shared__ float dsum[96];
    __shared__ float mu[64], isd[64];
    const int t = threadIdx.x;
    const int j = blockIdx.x & 255;
    const int b = blockIdx.x >> 8;
    const int l0 = j << 6;

    // stage u tile (spatial forward), float4 coalesced
    {
        const float4* up4 = (const float4*)(u + ((size_t)b * Ln + l0) * Cn);
        for (int e4 = t; e4 < 1536; e4 += 768) {
            int p = e4 / 24, c4 = e4 % 24;
            *(float4*)&uls[p * 100 + c4 * 4] = up4[e4];
        }
    }
    if (t < 96) dsum[t] = Ds[t] + Ds[Cn + t];
    __syncthreads();

    // x_dbl, both directions: 16 projections x 64 positions
    for (int dp = t; dp < 1024; dp += 768) {
        int dd = dp & 15, p = dp >> 4;
        const float4* wr = (const float4*)(xpw + dd * Cn);  // (K,8,C) flat
        const float4* ur = (const float4*)&uls[p * 100];
        float acc = 0.f;
#pragma unroll
        for (int c4 = 0; c4 < 24; ++c4) {
            float4 w = wr[c4], v = ur[c4];
            acc = fmaf(w.x, v.x, acc); acc = fmaf(w.y, v.y, acc);
            acc = fmaf(w.z, v.z, acc); acc = fmaf(w.w, v.w, acc);
        }
        xd[p * 16 + dd] = acc;
    }
    __syncthreads();

    // 8 chunk-scans: t -> (k, ci, c)
    const int c  = t % 96;
    const int ci = (t / 96) & 3;
    const int k  = t / 384;
    const int bk = b * Kn + k;
    const float Av = -__expf(Alogs[k * Cn + c]);
    const float bias = dtb[k * Cn + c];
    float dtwr[Rn];
#pragma unroll
    for (int r = 0; r < Rn; ++r) dtwr[r] = dtw[(k * Cn + c) * Rn + r];

    // k=0: chunk 4j+ci covers spatial p = ci*16 + i (i ascending)
    // k=1: chunk 1020-4j+ci covers spatial p = (3-ci)*16 + (15-i)
    const int chunk = (k == 0) ? (4 * j + ci) : (1020 - 4 * j + ci);
    float h = hinit[((size_t)bk * NCH + chunk) * Cn + c];
    const int xoff = k * 8;
    float yreg[SC];
#pragma unroll
    for (int i = 0; i < SC; ++i) {
        int p = (k == 0) ? (ci * 16 + i) : ((3 - ci) * 16 + (15 - i));
        const float* xr = &xd[p * 16 + xoff];
        float de = bias;
#pragma unroll
        for (int r = 0; r < Rn; ++r) de = fmaf(dtwr[r], xr[r], de);
        de = softplusf(de);
        float dA = __expf(de * Av);
        h = fmaf(dA, h, de * uls[p * 100 + c] * xr[6]);
        yreg[i] = h * xr[7];
    }

    if (k == 0) {
#pragma unroll
        for (int i = 0; i < SC; ++i) {
            int p = ci * 16 + i;
            yt[p * 104 + c] = yreg[i] + dsum[c] * uls[p * 100 + c];
        }
    }
    __syncthreads();
    if (k == 1) {
#pragma unroll
        for (int i = 0; i < SC; ++i) {
            int p = (3 - ci) * 16 + (15 - i);
            yt[p * 104 + c] += yreg[i];
        }
    }
    __syncthreads();

    // LN stats: first 256 threads, 4 per position, shuffle-combine
    if (t < 256) {
        const int p = t >> 2, q = t & 3;
        const float4* row = (const float4*)&yt[p * 104 + q * 24];
        float s = 0.f, ss = 0.f;
#pragma unroll
        for (int i = 0; i < 6; ++i) {
            float4 v = row[i];
            s += v.x + v.y + v.z + v.w;
            ss += v.x*v.x + v.y*v.y + v.z*v.z + v.w*v.w;
        }
        s  += __shfl_xor(s, 1);  s  += __shfl_xor(s, 2);
        ss += __shfl_xor(ss, 1); ss += __shfl_xor(ss, 2);
        if (q == 0) {
            float m = s * (1.f / Cn);
            mu[p] = m;
            isd[p] = rsqrtf(ss * (1.f / Cn) - m * m + 1e-5f);
        }
    }
    __syncthreads();

    // normalize + affine + gate, float4 coalesced
    {
        const float4* zp4 = (const float4*)(zs + ((size_t)b * Ln + l0) * Cn);
        const float4* w4  = (const float4*)onw;
        const float4* b4  = (const float4*)onb;
        float4* g4 = (float4*)(g + ((size_t)b * Ln + l0) * Cn);
        for (int e4 = t; e4 < 1536; e4 += 768) {
            int p = e4 / 24, c4 = e4 % 24;
            float4 v = *(const float4*)&yt[p * 104 + c4 * 4];
            float4 wv = w4[c4], bv = b4[c4], zv = zp4[e4];
            float m = mu[p], is = isd[p];
            float4 r;
            r.x = ((v.x - m) * is * wv.x + bv.x) * zv.x;
            r.y = ((v.y - m) * is * wv.y + bv.y) * zv.y;
            r.z = ((v.z - m) * is * wv.z + bv.z) * zv.z;
            r.w = ((v.w - m) * is * wv.w + bv.w) * zv.w;
            g4[e4] = r;
        }
    }
}

// ---------------------------------------------------------------------------
// Kernel E2: out_proj GEMM g (B,L,C) -> out (B,C,L), + scale_w.
// block = 256, tile 64 pos x 96 out, thread = 4 pos x 6 out, K chunked by 32.
// ---------------------------------------------------------------------------
__global__ __launch_bounds__(256) void k_scan3b(
    const float* __restrict__ g, const float* __restrict__ opw,
    const float* __restrict__ scw, float* __restrict__ out)
{
    __shared__ float gls[32 * 68];   // [k][p] pad 68
    __shared__ float wls[32 * 100];  // [k][o] pad 100
    const int t  = threadIdx.x;
    const int b  = blockIdx.x >> 8;
    const int l0 = (blockIdx.x & 255) << 6;
    const int tx = t & 15;           // 4 positions
    const int ty = t >> 4;           // 6 outputs

    float acc[6][4];
#pragma unroll
    for (int i = 0; i < 6; ++i)
#pragma unroll
        for (int j = 0; j < 4; ++j) acc[i][j] = 0.f;

    const float* gbase = g + ((size_t)b * Ln + l0) * Cn;

    for (int k0 = 0; k0 < Cn; k0 += 32) {
        if (k0) __syncthreads();
        for (int idx = t; idx < 2048; idx += 256) {
            int k = idx & 31, p = idx >> 5;
            gls[k * 68 + p] = gbase[(size_t)p * Cn + k0 + k];
        }
        for (int idx = t; idx < 3072; idx += 256) {
            int k = idx & 31, o = idx >> 5;
            wls[k * 100 + o] = opw[o * Cn + k0 + k];
        }
        __syncthreads();

#pragma unroll 8
        for (int kk = 0; kk < 32; ++kk) {
            float4 gv = *(const float4*)&gls[kk * 68 + tx * 4];
            const float* wr = &wls[kk * 100 + ty * 6];
            float ga[4] = {gv.x, gv.y, gv.z, gv.w};
#pragma unroll
            for (int i = 0; i < 6; ++i) {
                float w = wr[i];
#pragma unroll
                for (int jq = 0; jq < 4; ++jq)
                    acc[i][jq] = fmaf(w, ga[jq], acc[i][jq]);
            }
        }
    }

#pragma unroll
    for (int i = 0; i < 6; ++i) {
        const int o = ty * 6 + i;
        const float sc = scw[o];
        float4 st = make_float4(acc[i][0]*sc, acc[i][1]*sc, acc[i][2]*sc, acc[i][3]*sc);
        *(float4*)&out[((size_t)b * Cn + o) * Ln + l0 + tx * 4] = st;
    }
}

// ---------------------------------------------------------------------------
extern "C" void kernel_launch(void* const* d_in, const int* in_sizes, int n_in,
                              void* d_out, int out_size, void* d_ws, size_t ws_size,
                              hipStream_t stream)
{
    const float* x     = (const float*)d_in[0];
    const float* ipw   = (const float*)d_in[1];
    const float* cw    = (const float*)d_in[2];
    const float* cb    = (const float*)d_in[3];
    const float* xpw   = (const float*)d_in[4];
    const float* dtw   = (const float*)d_in[5];
    const float* dtb   = (const float*)d_in[6];
    const float* Alogs = (const float*)d_in[7];
    const float* Ds    = (const float*)d_in[8];
    const float* onw   = (const float*)d_in[9];
    const float* onb   = (const float*)d_in[10];
    const float* opw   = (const float*)d_in[11];
    const float* scw   = (const float*)d_in[12];
    float* out = (float*)d_out;

    float* wsp = (float*)d_ws;
    size_t off = 0;
    // xc dead after k_conv -> g aliases it
    float* xc   = wsp + off;
    float* g    = wsp + off; off += (size_t)Bn * Ln * Cn;         // 6.29M
    float* zs   = wsp + off; off += (size_t)Bn * Ln * Cn;         // 6.29M
    float* u    = wsp + off; off += (size_t)Bn * Ln * Cn;         // 6.29M
    float* Pc    = wsp + off; off += (size_t)Bn * Kn * NCH * Cn;  // 0.79M
    float* Qc    = wsp + off; off += (size_t)Bn * Kn * NCH * Cn;
    float* hinit = wsp + off; off += (size_t)Bn * Kn * NCH * Cn;
    // total ~21.2M floats ~85 MB

    k_inproj<<<Bn * 256, 256, 0, stream>>>(x, ipw, xc, zs);
    k_conv  <<<(Bn * Ln * Cn) / 256, 256, 0, stream>>>(xc, cw, cb, u);
    k_fscan1<<<Bn * Kn * 256, 384, 0, stream>>>(u, xpw, dtw, dtb, Alogs, Pc, Qc);
    k_scan2 <<<24, 1024, 0, stream>>>(Pc, Qc, hinit);
    k_scan3a<<<Bn * 256, 768, 0, stream>>>(u, xpw, dtw, dtb, Alogs, hinit,
                                           Ds, onw, onb, zs, g);
    k_scan3b<<<Bn * 256, 256, 0, stream>>>(g, opw, scw, out);
}

// Round 7
// 346.651 us; speedup vs baseline: 1.1840x; 1.1840x over previous
//
#include <hip/hip_runtime.h>
#include <math.h>

#define Bn 4
#define Cn 96
#define Hn 128
#define Wn 128
#define Ln (Hn*Wn)      // 16384
#define Kn 2
#define Rn 6
#define SC 16           // scan chunk length
#define NCH (Ln/SC)     // 1024 chunks per (b,k)

__device__ __forceinline__ float siluf(float x) { return x / (1.f + __expf(-x)); }
// native-instruction softplus: log1pf is a slow libm polynomial; __logf(1+e)
// is v_log_f32 with abs err < 1e-7 over our range (tolerance 2.5e-2).
__device__ __forceinline__ float softplusf(float x) {
    return fmaxf(x, 0.f) + __logf(1.f + __expf(-fabsf(x)));
}

// ---------------------------------------------------------------------------
// Kernel A: in_proj GEMM. x (B,C,L) -> xc (B,L,C), zs=silu(z) (B,L,C).
// block = 256 thr, tile 64 pos x 192 out, thread = 4 pos x 12 out.
// Epilogue stages the output tile in LDS so all global stores are coalesced
// float4 (scalar lane-strided stores caused 4.6x HBM write amplification).
// ---------------------------------------------------------------------------
__global__ __launch_bounds__(256, 4) void k_inproj(
    const float* __restrict__ x, const float* __restrict__ ipw,
    float* __restrict__ xc, float* __restrict__ zs)
{
    __shared__ float smem[2048 + 6272];  // xls(32x64) + wls(32x196) = 33.3 KB
    float* xls = smem;                   // [k][p]
    float* wls = smem + 2048;            // [k][o] pad 196
    float* stage = smem;                 // reused after K loop: [p][c] pad 100

    const int t  = threadIdx.x;
    const int b  = blockIdx.x >> 8;
    const int l0 = (blockIdx.x & 255) << 6;
    const int tx = t & 15;
    const int ty = t >> 4;

    float acc[12][4];
#pragma unroll
    for (int i = 0; i < 12; ++i)
#pragma unroll
        for (int j = 0; j < 4; ++j) acc[i][j] = 0.f;

    const float* xbase = x + (size_t)b * Cn * Ln + l0;

    for (int k0 = 0; k0 < Cn; k0 += 32) {
        if (k0) __syncthreads();
        {
            int idx = t;
#pragma unroll
            for (int q = 0; q < 2; ++q, idx += 256) {
                int k = idx >> 4, p4 = idx & 15;
                *(float4*)&xls[k * 64 + p4 * 4] =
                    *(const float4*)&xbase[(size_t)(k0 + k) * Ln + p4 * 4];
            }
        }
        for (int idx = t; idx < 32 * 192; idx += 256) {
            int o = idx % 192, k = idx / 192;
            wls[k * 196 + o] = ipw[o * Cn + k0 + k];
        }
        __syncthreads();

#pragma unroll 4
        for (int kk = 0; kk < 32; ++kk) {
            float4 xv = *(const float4*)&xls[kk * 64 + tx * 4];
            const float* wrow = &wls[kk * 196 + ty * 12];
            float4 w0 = *(const float4*)&wrow[0];
            float4 w1 = *(const float4*)&wrow[4];
            float4 w2 = *(const float4*)&wrow[8];
            float wv[12] = {w0.x,w0.y,w0.z,w0.w,w1.x,w1.y,w1.z,w1.w,w2.x,w2.y,w2.z,w2.w};
            float xa[4]  = {xv.x, xv.y, xv.z, xv.w};
#pragma unroll
            for (int i = 0; i < 12; ++i)
#pragma unroll
                for (int j = 0; j < 4; ++j)
                    acc[i][j] = fmaf(wv[i], xa[j], acc[i][j]);
        }
    }

    __syncthreads();
    if (ty < 8) {
#pragma unroll
        for (int j = 0; j < 4; ++j)
#pragma unroll
            for (int i = 0; i < 12; ++i)
                stage[(tx * 4 + j) * 100 + ty * 12 + i] = acc[i][j];
    }
    __syncthreads();
    {
        float4* dst = (float4*)(xc + ((size_t)b * Ln + l0) * Cn);
        for (int idx = t; idx < 1536; idx += 256) {
            int p = idx / 24, c4 = idx % 24;
            dst[idx] = *(const float4*)&stage[p * 100 + c4 * 4];
        }
    }
    __syncthreads();
    if (ty >= 8) {
#pragma unroll
        for (int j = 0; j < 4; ++j)
#pragma unroll
            for (int i = 0; i < 12; ++i)
                stage[(tx * 4 + j) * 100 + (ty - 8) * 12 + i] = siluf(acc[i][j]);
    }
    __syncthreads();
    {
        float4* dst = (float4*)(zs + ((size_t)b * Ln + l0) * Cn);
        for (int idx = t; idx < 1536; idx += 256) {
            int p = idx / 24, c4 = idx % 24;
            dst[idx] = *(const float4*)&stage[p * 100 + c4 * 4];
        }
    }
}

// ---------------------------------------------------------------------------
// Kernel B: depthwise 3x3 conv (SAME) + bias + SiLU.  xc (B,L,C) -> u (B,L,C).
// ---------------------------------------------------------------------------
__global__ __launch_bounds__(256) void k_conv(
    const float* __restrict__ xc, const float* __restrict__ cw,
    const float* __restrict__ cb, float* __restrict__ u)
{
    const int e   = blockIdx.x * 256 + threadIdx.x;
    const int c   = e % Cn;
    const int pos = e / Cn;
    const int l   = pos % Ln;
    const int b   = pos / Ln;
    const int h   = l >> 7, w = l & 127;

    float acc = cb[c];
#pragma unroll
    for (int dh = -1; dh <= 1; ++dh) {
        int hh = h + dh;
        if (hh < 0 || hh >= Hn) continue;
#pragma unroll
        for (int dw = -1; dw <= 1; ++dw) {
            int ww = w + dw;
            if (ww < 0 || ww >= Wn) continue;
            acc = fmaf(cw[c*9 + (dh+1)*3 + (dw+1)],
                       xc[((size_t)b * Ln + (hh << 7) + ww) * Cn + c], acc);
        }
    }
    u[e] = siluf(acc);
}

// ---------------------------------------------------------------------------
// Kernel C: carry-only fused x_dbl + delta + local scan.
// 384 thr = 4 chunks x 96 channels, tile = 64 scan positions.
// Scan restructured into half-batches of 8: all (dA,dBu) computed first with
// full ILP (transcendentals pipeline, no h-dependence), then a pure-fma chain.
// ---------------------------------------------------------------------------
__global__ __launch_bounds__(384) void k_fscan1(
    const float* __restrict__ u, const float* __restrict__ xpw,
    const float* __restrict__ dtw, const float* __restrict__ dtb,
    const float* __restrict__ Alogs,
    float* __restrict__ Pc, float* __restrict__ Qc)
{
    __shared__ float uls[64 * 100];  // [p][c] pad 100
    __shared__ float xd[64 * 8];     // [p][d]
    const int t   = threadIdx.x;
    const int seg = blockIdx.x & 255;
    const int k   = (blockIdx.x >> 8) & 1;
    const int b   = blockIdx.x >> 9;
    const int bk  = b * Kn + k;
    const int l0  = seg << 6;        // scan-position base (64 positions)

    if (k == 0) {
        const float* up = u + ((size_t)b * Ln + l0) * Cn;
        for (int idx = t; idx < 64 * Cn; idx += 384) {
            int p = idx / Cn, c = idx % Cn;
            uls[p * 100 + c] = up[idx];
        }
    } else {
        const float* up = u + ((size_t)b * Ln + (Ln - 64 - l0)) * Cn;
        for (int idx = t; idx < 64 * Cn; idx += 384) {
            int p = 63 - idx / Cn, c = idx % Cn;
            uls[p * 100 + c] = up[idx];
        }
    }
    __syncthreads();

    // x_dbl: 8 projections x 64 positions
    for (int dp = t; dp < 512; dp += 384) {
        int d = dp & 7, p = dp >> 3;
        const float4* wr = (const float4*)(xpw + (k * 8 + d) * Cn);
        const float4* ur = (const float4*)&uls[p * 100];
        float acc = 0.f;
#pragma unroll
        for (int c4 = 0; c4 < 24; ++c4) {
            float4 w = wr[c4], v = ur[c4];
            acc = fmaf(w.x, v.x, acc); acc = fmaf(w.y, v.y, acc);
            acc = fmaf(w.z, v.z, acc); acc = fmaf(w.w, v.w, acc);
        }
        xd[p * 8 + d] = acc;
    }
    __syncthreads();

    const int c  = t % Cn;
    const int ci = t / Cn;           // chunk within tile: 0..3
    const int pbase = ci * SC;
    const float Av = -__expf(Alogs[k * Cn + c]);
    const float bias = dtb[k * Cn + c];
    float dtwr[Rn];
#pragma unroll
    for (int r = 0; r < Rn; ++r) dtwr[r] = dtw[(k * Cn + c) * Rn + r];

    float h = 0.f, cp = 1.f;
#pragma unroll
    for (int half = 0; half < 2; ++half) {
        float dAv[8], dBu[8];
#pragma unroll
        for (int i = 0; i < 8; ++i) {
            const int p = pbase + half * 8 + i;
            const float* xr = &xd[p * 8];
            float de = bias;
#pragma unroll
            for (int r = 0; r < Rn; ++r) de = fmaf(dtwr[r], xr[r], de);
            de = softplusf(de);
            dAv[i] = __expf(de * Av);
            dBu[i] = de * uls[p * 100 + c] * xr[6];
        }
#pragma unroll
        for (int i = 0; i < 8; ++i) {
            h = fmaf(dAv[i], h, dBu[i]);
            cp *= dAv[i];
        }
    }
    const size_t cidx = ((size_t)bk * NCH + seg * 4 + ci) * Cn + c;
    Pc[cidx] = cp;
    Qc[cidx] = h;
}

// ---------------------------------------------------------------------------
// Kernel D: hierarchical carry scan. 768 series x 1024 chunks.
// Grid = 24 blocks (8 bk x 3 channel-slices of 32), block = 1024 thr (32c x 32g),
// group = 32 chunks: 32-step group carry, 32-step serial, 32-step replay.
// ---------------------------------------------------------------------------
__global__ __launch_bounds__(1024) void k_scan2(
    const float* __restrict__ Pc, const float* __restrict__ Qc,
    float* __restrict__ hinit)
{
    __shared__ float Pg[32][33], Qg[32][33], gini[32][33];
    const int bk    = blockIdx.x / 3;
    const int cbase = (blockIdx.x % 3) * 32;
    const int t = threadIdx.x;
    const int c = t & 31, g = t >> 5;

    const size_t base = ((size_t)bk * NCH + g * 32) * Cn + cbase + c;
    float P = 1.f, Q = 0.f;
    for (int j = 0; j < 32; ++j) {
        size_t idx = base + (size_t)j * Cn;
        float p_ = Pc[idx], q_ = Qc[idx];
        Q = fmaf(p_, Q, q_);
        P *= p_;
    }
    Pg[g][c] = P; Qg[g][c] = Q;
    __syncthreads();
    if (t < 32) {
        float h = 0.f;
        for (int gg = 0; gg < 32; ++gg) {
            gini[gg][t] = h;
            h = fmaf(Pg[gg][t], h, Qg[gg][t]);
        }
    }
    __syncthreads();
    float h = gini[g][c];
    for (int j = 0; j < 32; ++j) {
        size_t idx = base + (size_t)j * Cn;
        hinit[idx] = h;
        h = fmaf(Pc[idx], h, Qc[idx]);
    }
}

// ---------------------------------------------------------------------------
// Kernel E1: recompute + merge + LayerNorm + gate.
// Block = (b, 64-pos spatial tile), 768 thr = 2 dirs x 4 chunks x 96 channels.
// Same half-batch ILP restructure of the scan as k_fscan1.
// ---------------------------------------------------------------------------
__global__ __launch_bounds__(768) void k_scan3a(
    const float* __restrict__ u, const float* __restrict__ xpw,
    const float* __restrict__ dtw, const float* __restrict__ dtb,
    const float* __restrict__ Alogs, const float* __restrict__ hinit,
    const float* __restrict__ Ds, const float* __restrict__ onw,
    const float* __restrict__ onb, const float* __restrict__ zs,
    float* __restrict__ g)
{
    __shared__ float uls[64 * 100];  // 25.6 KB [p][c]
    __shared__ float xd[64 * 16];    //  4.1 KB [p][dd] dd=k*8+d
    __shared__ float yt[64 * 104];   // 26.6 KB [p][c]
    __shared__ float dsum[96];
    __shared__ float mu[64], isd[64];
    const int t = threadIdx.x;
    const int j = blockIdx.x & 255;
    const int b = blockIdx.x >> 8;
    const int l0 = j << 6;

    {
        const float4* up4 = (const float4*)(u + ((size_t)b * Ln + l0) * Cn);
        for (int e4 = t; e4 < 1536; e4 += 768) {
            int p = e4 / 24, c4 = e4 % 24;
            *(float4*)&uls[p * 100 + c4 * 4] = up4[e4];
        }
    }
    if (t < 96) dsum[t] = Ds[t] + Ds[Cn + t];
    __syncthreads();

    // x_dbl, both directions: 16 projections x 64 positions
    for (int dp = t; dp < 1024; dp += 768) {
        int dd = dp & 15, p = dp >> 4;
        const float4* wr = (const float4*)(xpw + dd * Cn);  // (K,8,C) flat
        const float4* ur = (const float4*)&uls[p * 100];
        float acc = 0.f;
#pragma unroll
        for (int c4 = 0; c4 < 24; ++c4) {
            float4 w = wr[c4], v = ur[c4];
            acc = fmaf(w.x, v.x, acc); acc = fmaf(w.y, v.y, acc);
            acc = fmaf(w.z, v.z, acc); acc = fmaf(w.w, v.w, acc);
        }
        xd[p * 16 + dd] = acc;
    }
    __syncthreads();

    // 8 chunk-scans: t -> (k, ci, c)
    const int c  = t % 96;
    const int ci = (t / 96) & 3;
    const int k  = t / 384;
    const int bk = b * Kn + k;
    const float Av = -__expf(Alogs[k * Cn + c]);
    const float bias = dtb[k * Cn + c];
    float dtwr[Rn];
#pragma unroll
    for (int r = 0; r < Rn; ++r) dtwr[r] = dtw[(k * Cn + c) * Rn + r];

    // k=0: chunk 4j+ci covers spatial p = ci*16 + i (i ascending)
    // k=1: chunk 1020-4j+ci covers spatial p = (3-ci)*16 + (15-i)
    const int chunk = (k == 0) ? (4 * j + ci) : (1020 - 4 * j + ci);
    float h = hinit[((size_t)bk * NCH + chunk) * Cn + c];
    const int xoff = k * 8;
    float yreg[SC];
#pragma unroll
    for (int half = 0; half < 2; ++half) {
        float dAv[8], dBu[8];
#pragma unroll
        for (int i = 0; i < 8; ++i) {
            const int ii = half * 8 + i;
            const int p = (k == 0) ? (ci * 16 + ii) : ((3 - ci) * 16 + (15 - ii));
            const float* xr = &xd[p * 16 + xoff];
            float de = bias;
#pragma unroll
            for (int r = 0; r < Rn; ++r) de = fmaf(dtwr[r], xr[r], de);
            de = softplusf(de);
            dAv[i] = __expf(de * Av);
            dBu[i] = de * uls[p * 100 + c] * xr[6];
        }
#pragma unroll
        for (int i = 0; i < 8; ++i) {
            const int ii = half * 8 + i;
            const int p = (k == 0) ? (ci * 16 + ii) : ((3 - ci) * 16 + (15 - ii));
            h = fmaf(dAv[i], h, dBu[i]);
            yreg[ii] = h * xd[p * 16 + xoff + 7];
        }
    }

    if (k == 0) {
#pragma unroll
        for (int i = 0; i < SC; ++i) {
            int p = ci * 16 + i;
            yt[p * 104 + c] = yreg[i] + dsum[c] * uls[p * 100 + c];
        }
    }
    __syncthreads();
    if (k == 1) {
#pragma unroll
        for (int i = 0; i < SC; ++i) {
            int p = (3 - ci) * 16 + (15 - i);
            yt[p * 104 + c] += yreg[i];
        }
    }
    __syncthreads();

    // LN stats: first 256 threads, 4 per position, shuffle-combine
    if (t < 256) {
        const int p = t >> 2, q = t & 3;
        const float4* row = (const float4*)&yt[p * 104 + q * 24];
        float s = 0.f, ss = 0.f;
#pragma unroll
        for (int i = 0; i < 6; ++i) {
            float4 v = row[i];
            s += v.x + v.y + v.z + v.w;
            ss += v.x*v.x + v.y*v.y + v.z*v.z + v.w*v.w;
        }
        s  += __shfl_xor(s, 1);  s  += __shfl_xor(s, 2);
        ss += __shfl_xor(ss, 1); ss += __shfl_xor(ss, 2);
        if (q == 0) {
            float m = s * (1.f / Cn);
            mu[p] = m;
            isd[p] = rsqrtf(ss * (1.f / Cn) - m * m + 1e-5f);
        }
    }
    __syncthreads();

    {
        const float4* zp4 = (const float4*)(zs + ((size_t)b * Ln + l0) * Cn);
        const float4* w4  = (const float4*)onw;
        const float4* b4  = (const float4*)onb;
        float4* g4 = (float4*)(g + ((size_t)b * Ln + l0) * Cn);
        for (int e4 = t; e4 < 1536; e4 += 768) {
            int p = e4 / 24, c4 = e4 % 24;
            float4 v = *(const float4*)&yt[p * 104 + c4 * 4];
            float4 wv = w4[c4], bv = b4[c4], zv = zp4[e4];
            float m = mu[p], is = isd[p];
            float4 r;
            r.x = ((v.x - m) * is * wv.x + bv.x) * zv.x;
            r.y = ((v.y - m) * is * wv.y + bv.y) * zv.y;
            r.z = ((v.z - m) * is * wv.z + bv.z) * zv.z;
            r.w = ((v.w - m) * is * wv.w + bv.w) * zv.w;
            g4[e4] = r;
        }
    }
}

// ---------------------------------------------------------------------------
// Kernel E2: out_proj GEMM g (B,L,C) -> out (B,C,L), + scale_w.
// block = 256, tile 64 pos x 96 out, thread = 4 pos x 6 out, K chunked by 32.
// ---------------------------------------------------------------------------
__global__ __launch_bounds__(256) void k_scan3b(
    const float* __restrict__ g, const float* __restrict__ opw,
    const float* __restrict__ scw, float* __restrict__ out)
{
    __shared__ float gls[32 * 68];   // [k][p] pad 68
    __shared__ float wls[32 * 100];  // [k][o] pad 100
    const int t  = threadIdx.x;
    const int b  = blockIdx.x >> 8;
    const int l0 = (blockIdx.x & 255) << 6;
    const int tx = t & 15;           // 4 positions
    const int ty = t >> 4;           // 6 outputs

    float acc[6][4];
#pragma unroll
    for (int i = 0; i < 6; ++i)
#pragma unroll
        for (int j = 0; j < 4; ++j) acc[i][j] = 0.f;

    const float* gbase = g + ((size_t)b * Ln + l0) * Cn;

    for (int k0 = 0; k0 < Cn; k0 += 32) {
        if (k0) __syncthreads();
        for (int idx = t; idx < 2048; idx += 256) {
            int k = idx & 31, p = idx >> 5;
            gls[k * 68 + p] = gbase[(size_t)p * Cn + k0 + k];
        }
        for (int idx = t; idx < 3072; idx += 256) {
            int k = idx & 31, o = idx >> 5;
            wls[k * 100 + o] = opw[o * Cn + k0 + k];
        }
        __syncthreads();

#pragma unroll 8
        for (int kk = 0; kk < 32; ++kk) {
            float4 gv = *(const float4*)&gls[kk * 68 + tx * 4];
            const float* wr = &wls[kk * 100 + ty * 6];
            float ga[4] = {gv.x, gv.y, gv.z, gv.w};
#pragma unroll
            for (int i = 0; i < 6; ++i) {
                float w = wr[i];
#pragma unroll
                for (int jq = 0; jq < 4; ++jq)
                    acc[i][jq] = fmaf(w, ga[jq], acc[i][jq]);
            }
        }
    }

#pragma unroll
    for (int i = 0; i < 6; ++i) {
        const int o = ty * 6 + i;
        const float sc = scw[o];
        float4 st = make_float4(acc[i][0]*sc, acc[i][1]*sc, acc[i][2]*sc, acc[i][3]*sc);
        *(float4*)&out[((size_t)b * Cn + o) * Ln + l0 + tx * 4] = st;
    }
}

// ---------------------------------------------------------------------------
extern "C" void kernel_launch(void* const* d_in, const int* in_sizes, int n_in,
                              void* d_out, int out_size, void* d_ws, size_t ws_size,
                              hipStream_t stream)
{
    const float* x     = (const float*)d_in[0];
    const float* ipw   = (const float*)d_in[1];
    const float* cw    = (const float*)d_in[2];
    const float* cb    = (const float*)d_in[3];
    const float* xpw   = (const float*)d_in[4];
    const float* dtw   = (const float*)d_in[5];
    const float* dtb   = (const float*)d_in[6];
    const float* Alogs = (const float*)d_in[7];
    const float* Ds    = (const float*)d_in[8];
    const float* onw   = (const float*)d_in[9];
    const float* onb   = (const float*)d_in[10];
    const float* opw   = (const float*)d_in[11];
    const float* scw   = (const float*)d_in[12];
    float* out = (float*)d_out;

    float* wsp = (float*)d_ws;
    size_t off = 0;
    // xc dead after k_conv -> g aliases it
    float* xc   = wsp + off;
    float* g    = wsp + off; off += (size_t)Bn * Ln * Cn;         // 6.29M
    float* zs   = wsp + off; off += (size_t)Bn * Ln * Cn;         // 6.29M
    float* u    = wsp + off; off += (size_t)Bn * Ln * Cn;         // 6.29M
    float* Pc    = wsp + off; off += (size_t)Bn * Kn * NCH * Cn;  // 0.79M
    float* Qc    = wsp + off; off += (size_t)Bn * Kn * NCH * Cn;
    float* hinit = wsp + off; off += (size_t)Bn * Kn * NCH * Cn;

    k_inproj<<<Bn * 256, 256, 0, stream>>>(x, ipw, xc, zs);
    k_conv  <<<(Bn * Ln * Cn) / 256, 256, 0, stream>>>(xc, cw, cb, u);
    k_fscan1<<<Bn * Kn * 256, 384, 0, stream>>>(u, xpw, dtw, dtb, Alogs, Pc, Qc);
    k_scan2 <<<24, 1024, 0, stream>>>(Pc, Qc, hinit);
    k_scan3a<<<Bn * 256, 768, 0, stream>>>(u, xpw, dtw, dtb, Alogs, hinit,
                                           Ds, onw, onb, zs, g);
    k_scan3b<<<Bn * 256, 256, 0, stream>>>(g, opw, scw, out);
}

// Round 8
// 330.645 us; speedup vs baseline: 1.2414x; 1.0484x over previous
//
#include <hip/hip_runtime.h>
#include <math.h>

#define Bn 4
#define Cn 96
#define Hn 128
#define Wn 128
#define Ln (Hn*Wn)      // 16384
#define Kn 2
#define Rn 6
#define SC 16           // scan chunk length
#define NCH (Ln/SC)     // 1024 chunks per (b,k)

__device__ __forceinline__ float siluf(float x) { return x / (1.f + __expf(-x)); }
// native-instruction softplus: log1pf is a slow libm polynomial; __logf(1+e)
// is v_log_f32 with abs err < 1e-7 over our range (tolerance 2.5e-2).
__device__ __forceinline__ float softplusf(float x) {
    return fmaxf(x, 0.f) + __logf(1.f + __expf(-fabsf(x)));
}

// ---------------------------------------------------------------------------
// Kernel A: in_proj GEMM. x (B,C,L) -> xc (B,L,C), zs=silu(z) (B,L,C).
// block = 256 thr, tile 128 pos x 192 out, thread = 8 pos x 12 out (96 acc).
// Positions per thread split {tx*4, 64+tx*4} so LDS reads stay 2-way (free).
// Epilogue stages halves through LDS for coalesced float4 stores.
// ---------------------------------------------------------------------------
__global__ __launch_bounds__(256, 3) void k_inproj(
    const float* __restrict__ x, const float* __restrict__ ipw,
    float* __restrict__ xc, float* __restrict__ zs)
{
    __shared__ float smem[4096 + 6272];  // xls(32x128)=16KB + wls(32x196)=25KB
    float* xls = smem;                   // [k][p] stride 128
    float* wls = smem + 4096;            // [k][o] stride 196
    float* stage = smem;                 // reused: [p(64)][c] stride 100

    const int t  = threadIdx.x;
    const int b  = blockIdx.x >> 7;
    const int l0 = (blockIdx.x & 127) << 7;
    const int tx = t & 15;
    const int ty = t >> 4;

    float acc[12][8];   // [out][pos]: j<4 -> tx*4+j ; j>=4 -> 64+tx*4+(j-4)
#pragma unroll
    for (int i = 0; i < 12; ++i)
#pragma unroll
        for (int j = 0; j < 8; ++j) acc[i][j] = 0.f;

    const float* xbase = x + (size_t)b * Cn * Ln + l0;

    for (int k0 = 0; k0 < Cn; k0 += 32) {
        if (k0) __syncthreads();
        // x chunk: 32x128 floats = 1024 float4, 4 per thread, coalesced
        {
            int idx = t;
#pragma unroll
            for (int q = 0; q < 4; ++q, idx += 256) {
                int k = idx >> 5, p4 = idx & 31;
                *(float4*)&xls[k * 128 + p4 * 4] =
                    *(const float4*)&xbase[(size_t)(k0 + k) * Ln + p4 * 4];
            }
        }
        // w chunk: 32x192 floats
        for (int idx = t; idx < 32 * 192; idx += 256) {
            int o = idx % 192, k = idx / 192;
            wls[k * 196 + o] = ipw[o * Cn + k0 + k];
        }
        __syncthreads();

#pragma unroll 2
        for (int kk = 0; kk < 32; ++kk) {
            float4 xv0 = *(const float4*)&xls[kk * 128 + tx * 4];
            float4 xv1 = *(const float4*)&xls[kk * 128 + 64 + tx * 4];
            const float* wrow = &wls[kk * 196 + ty * 12];
            float4 w0 = *(const float4*)&wrow[0];
            float4 w1 = *(const float4*)&wrow[4];
            float4 w2 = *(const float4*)&wrow[8];
            float wv[12] = {w0.x,w0.y,w0.z,w0.w,w1.x,w1.y,w1.z,w1.w,w2.x,w2.y,w2.z,w2.w};
            float xa[8]  = {xv0.x,xv0.y,xv0.z,xv0.w,xv1.x,xv1.y,xv1.z,xv1.w};
#pragma unroll
            for (int i = 0; i < 12; ++i)
#pragma unroll
                for (int j = 0; j < 8; ++j)
                    acc[i][j] = fmaf(wv[i], xa[j], acc[i][j]);
        }
    }

    // ---- epilogue: LDS-staged coalesced stores, 2 halves x {xc, zs} ----
    const size_t tilebase = (size_t)b * Ln + l0;
#pragma unroll
    for (int half = 0; half < 2; ++half) {
        __syncthreads();
        if (ty < 8) {
#pragma unroll
            for (int j = 0; j < 4; ++j)
#pragma unroll
                for (int i = 0; i < 12; ++i)
                    stage[(tx * 4 + j) * 100 + ty * 12 + i] = acc[i][half * 4 + j];
        }
        __syncthreads();
        {
            float4* dst = (float4*)(xc + (tilebase + half * 64) * Cn);
            for (int idx = t; idx < 1536; idx += 256) {
                int p = idx / 24, c4 = idx % 24;
                dst[idx] = *(const float4*)&stage[p * 100 + c4 * 4];
            }
        }
        __syncthreads();
        if (ty >= 8) {
#pragma unroll
            for (int j = 0; j < 4; ++j)
#pragma unroll
                for (int i = 0; i < 12; ++i)
                    stage[(tx * 4 + j) * 100 + (ty - 8) * 12 + i] = siluf(acc[i][half * 4 + j]);
        }
        __syncthreads();
        {
            float4* dst = (float4*)(zs + (tilebase + half * 64) * Cn);
            for (int idx = t; idx < 1536; idx += 256) {
                int p = idx / 24, c4 = idx % 24;
                dst[idx] = *(const float4*)&stage[p * 100 + c4 * 4];
            }
        }
    }
}

// ---------------------------------------------------------------------------
// Kernel B: depthwise 3x3 conv (SAME) + bias + SiLU.  xc (B,L,C) -> u (B,L,C).
// ---------------------------------------------------------------------------
__global__ __launch_bounds__(256) void k_conv(
    const float* __restrict__ xc, const float* __restrict__ cw,
    const float* __restrict__ cb, float* __restrict__ u)
{
    const int e   = blockIdx.x * 256 + threadIdx.x;
    const int c   = e % Cn;
    const int pos = e / Cn;
    const int l   = pos % Ln;
    const int b   = pos / Ln;
    const int h   = l >> 7, w = l & 127;

    float acc = cb[c];
#pragma unroll
    for (int dh = -1; dh <= 1; ++dh) {
        int hh = h + dh;
        if (hh < 0 || hh >= Hn) continue;
#pragma unroll
        for (int dw = -1; dw <= 1; ++dw) {
            int ww = w + dw;
            if (ww < 0 || ww >= Wn) continue;
            acc = fmaf(cw[c*9 + (dh+1)*3 + (dw+1)],
                       xc[((size_t)b * Ln + (hh << 7) + ww) * Cn + c], acc);
        }
    }
    u[e] = siluf(acc);
}

// ---------------------------------------------------------------------------
// Kernel C: carry-only fused x_dbl + delta + local scan.
// 384 thr = 4 chunks x 96 channels, tile = 64 scan positions.
// Scan in half-batches of 8: (dA,dBu) with full ILP, then pure-fma chain.
// ---------------------------------------------------------------------------
__global__ __launch_bounds__(384) void k_fscan1(
    const float* __restrict__ u, const float* __restrict__ xpw,
    const float* __restrict__ dtw, const float* __restrict__ dtb,
    const float* __restrict__ Alogs,
    float* __restrict__ Pc, float* __restrict__ Qc)
{
    __shared__ float uls[64 * 100];  // [p][c] pad 100
    __shared__ float xd[64 * 8];     // [p][d]
    const int t   = threadIdx.x;
    const int seg = blockIdx.x & 255;
    const int k   = (blockIdx.x >> 8) & 1;
    const int b   = blockIdx.x >> 9;
    const int bk  = b * Kn + k;
    const int l0  = seg << 6;        // scan-position base (64 positions)

    if (k == 0) {
        const float* up = u + ((size_t)b * Ln + l0) * Cn;
        for (int idx = t; idx < 64 * Cn; idx += 384) {
            int p = idx / Cn, c = idx % Cn;
            uls[p * 100 + c] = up[idx];
        }
    } else {
        const float* up = u + ((size_t)b * Ln + (Ln - 64 - l0)) * Cn;
        for (int idx = t; idx < 64 * Cn; idx += 384) {
            int p = 63 - idx / Cn, c = idx % Cn;
            uls[p * 100 + c] = up[idx];
        }
    }
    __syncthreads();

    // x_dbl: 8 projections x 64 positions
    for (int dp = t; dp < 512; dp += 384) {
        int d = dp & 7, p = dp >> 3;
        const float4* wr = (const float4*)(xpw + (k * 8 + d) * Cn);
        const float4* ur = (const float4*)&uls[p * 100];
        float acc = 0.f;
#pragma unroll
        for (int c4 = 0; c4 < 24; ++c4) {
            float4 w = wr[c4], v = ur[c4];
            acc = fmaf(w.x, v.x, acc); acc = fmaf(w.y, v.y, acc);
            acc = fmaf(w.z, v.z, acc); acc = fmaf(w.w, v.w, acc);
        }
        xd[p * 8 + d] = acc;
    }
    __syncthreads();

    const int c  = t % Cn;
    const int ci = t / Cn;           // chunk within tile: 0..3
    const int pbase = ci * SC;
    const float Av = -__expf(Alogs[k * Cn + c]);
    const float bias = dtb[k * Cn + c];
    float dtwr[Rn];
#pragma unroll
    for (int r = 0; r < Rn; ++r) dtwr[r] = dtw[(k * Cn + c) * Rn + r];

    float h = 0.f, cp = 1.f;
#pragma unroll
    for (int half = 0; half < 2; ++half) {
        float dAv[8], dBu[8];
#pragma unroll
        for (int i = 0; i < 8; ++i) {
            const int p = pbase + half * 8 + i;
            const float* xr = &xd[p * 8];
            float de = bias;
#pragma unroll
            for (int r = 0; r < Rn; ++r) de = fmaf(dtwr[r], xr[r], de);
            de = softplusf(de);
            dAv[i] = __expf(de * Av);
            dBu[i] = de * uls[p * 100 + c] * xr[6];
        }
#pragma unroll
        for (int i = 0; i < 8; ++i) {
            h = fmaf(dAv[i], h, dBu[i]);
            cp *= dAv[i];
        }
    }
    const size_t cidx = ((size_t)bk * NCH + seg * 4 + ci) * Cn + c;
    Pc[cidx] = cp;
    Qc[cidx] = h;
}

// ---------------------------------------------------------------------------
// Kernel D: hierarchical carry scan. 768 series x 1024 chunks.
// Grid = 24 blocks (8 bk x 3 channel-slices of 32), block = 1024 thr (32c x 32g),
// group = 32 chunks: 32-step group carry, 32-step serial, 32-step replay.
// ---------------------------------------------------------------------------
__global__ __launch_bounds__(1024) void k_scan2(
    const float* __restrict__ Pc, const float* __restrict__ Qc,
    float* __restrict__ hinit)
{
    __shared__ float Pg[32][33], Qg[32][33], gini[32][33];
    const int bk    = blockIdx.x / 3;
    const int cbase = (blockIdx.x % 3) * 32;
    const int t = threadIdx.x;
    const int c = t & 31, g = t >> 5;

    const size_t base = ((size_t)bk * NCH + g * 32) * Cn + cbase + c;
    float P = 1.f, Q = 0.f;
    for (int j = 0; j < 32; ++j) {
        size_t idx = base + (size_t)j * Cn;
        float p_ = Pc[idx], q_ = Qc[idx];
        Q = fmaf(p_, Q, q_);
        P *= p_;
    }
    Pg[g][c] = P; Qg[g][c] = Q;
    __syncthreads();
    if (t < 32) {
        float h = 0.f;
        for (int gg = 0; gg < 32; ++gg) {
            gini[gg][t] = h;
            h = fmaf(Pg[gg][t], h, Qg[gg][t]);
        }
    }
    __syncthreads();
    float h = gini[g][c];
    for (int j = 0; j < 32; ++j) {
        size_t idx = base + (size_t)j * Cn;
        hinit[idx] = h;
        h = fmaf(Pc[idx], h, Qc[idx]);
    }
}

// ---------------------------------------------------------------------------
// Kernel E1: recompute + merge + LayerNorm + gate.
// Block = (b, 64-pos spatial tile), 768 thr = 2 dirs x 4 chunks x 96 channels.
// ---------------------------------------------------------------------------
__global__ __launch_bounds__(768) void k_scan3a(
    const float* __restrict__ u, const float* __restrict__ xpw,
    const float* __restrict__ dtw, const float* __restrict__ dtb,
    const float* __restrict__ Alogs, const float* __restrict__ hinit,
    const float* __restrict__ Ds, const float* __restrict__ onw,
    const float* __restrict__ onb, const float* __restrict__ zs,
    float* __restrict__ g)
{
    __shared__ float uls[64 * 100];  // 25.6 KB [p][c]
    __shared__ float xd[64 * 16];    //  4.1 KB [p][dd] dd=k*8+d
    __shared__ float yt[64 * 104];   // 26.6 KB [p][c]
    __shared__ float dsum[96];
    __shared__ float mu[64], isd[64];
    const int t = threadIdx.x;
    const int j = blockIdx.x & 255;
    const int b = blockIdx.x >> 8;
    const int l0 = j << 6;

    {
        const float4* up4 = (const float4*)(u + ((size_t)b * Ln + l0) * Cn);
        for (int e4 = t; e4 < 1536; e4 += 768) {
            int p = e4 / 24, c4 = e4 % 24;
            *(float4*)&uls[p * 100 + c4 * 4] = up4[e4];
        }
    }
    if (t < 96) dsum[t] = Ds[t] + Ds[Cn + t];
    __syncthreads();

    // x_dbl, both directions: 16 projections x 64 positions
    for (int dp = t; dp < 1024; dp += 768) {
        int dd = dp & 15, p = dp >> 4;
        const float4* wr = (const float4*)(xpw + dd * Cn);  // (K,8,C) flat
        const float4* ur = (const float4*)&uls[p * 100];
        float acc = 0.f;
#pragma unroll
        for (int c4 = 0; c4 < 24; ++c4) {
            float4 w = wr[c4], v = ur[c4];
            acc = fmaf(w.x, v.x, acc); acc = fmaf(w.y, v.y, acc);
            acc = fmaf(w.z, v.z, acc); acc = fmaf(w.w, v.w, acc);
        }
        xd[p * 16 + dd] = acc;
    }
    __syncthreads();

    // 8 chunk-scans: t -> (k, ci, c)
    const int c  = t % 96;
    const int ci = (t / 96) & 3;
    const int k  = t / 384;
    const int bk = b * Kn + k;
    const float Av = -__expf(Alogs[k * Cn + c]);
    const float bias = dtb[k * Cn + c];
    float dtwr[Rn];
#pragma unroll
    for (int r = 0; r < Rn; ++r) dtwr[r] = dtw[(k * Cn + c) * Rn + r];

    // k=0: chunk 4j+ci covers spatial p = ci*16 + i (i ascending)
    // k=1: chunk 1020-4j+ci covers spatial p = (3-ci)*16 + (15-i)
    const int chunk = (k == 0) ? (4 * j + ci) : (1020 - 4 * j + ci);
    float h = hinit[((size_t)bk * NCH + chunk) * Cn + c];
    const int xoff = k * 8;
    float yreg[SC];
#pragma unroll
    for (int half = 0; half < 2; ++half) {
        float dAv[8], dBu[8];
#pragma unroll
        for (int i = 0; i < 8; ++i) {
            const int ii = half * 8 + i;
            const int p = (k == 0) ? (ci * 16 + ii) : ((3 - ci) * 16 + (15 - ii));
            const float* xr = &xd[p * 16 + xoff];
            float de = bias;
#pragma unroll
            for (int r = 0; r < Rn; ++r) de = fmaf(dtwr[r], xr[r], de);
            de = softplusf(de);
            dAv[i] = __expf(de * Av);
            dBu[i] = de * uls[p * 100 + c] * xr[6];
        }
#pragma unroll
        for (int i = 0; i < 8; ++i) {
            const int ii = half * 8 + i;
            const int p = (k == 0) ? (ci * 16 + ii) : ((3 - ci) * 16 + (15 - ii));
            h = fmaf(dAv[i], h, dBu[i]);
            yreg[ii] = h * xd[p * 16 + xoff + 7];
        }
    }

    if (k == 0) {
#pragma unroll
        for (int i = 0; i < SC; ++i) {
            int p = ci * 16 + i;
            yt[p * 104 + c] = yreg[i] + dsum[c] * uls[p * 100 + c];
        }
    }
    __syncthreads();
    if (k == 1) {
#pragma unroll
        for (int i = 0; i < SC; ++i) {
            int p = (3 - ci) * 16 + (15 - i);
            yt[p * 104 + c] += yreg[i];
        }
    }
    __syncthreads();

    // LN stats: first 256 threads, 4 per position, shuffle-combine
    if (t < 256) {
        const int p = t >> 2, q = t & 3;
        const float4* row = (const float4*)&yt[p * 104 + q * 24];
        float s = 0.f, ss = 0.f;
#pragma unroll
        for (int i = 0; i < 6; ++i) {
            float4 v = row[i];
            s += v.x + v.y + v.z + v.w;
            ss += v.x*v.x + v.y*v.y + v.z*v.z + v.w*v.w;
        }
        s  += __shfl_xor(s, 1);  s  += __shfl_xor(s, 2);
        ss += __shfl_xor(ss, 1); ss += __shfl_xor(ss, 2);
        if (q == 0) {
            float m = s * (1.f / Cn);
            mu[p] = m;
            isd[p] = rsqrtf(ss * (1.f / Cn) - m * m + 1e-5f);
        }
    }
    __syncthreads();

    {
        const float4* zp4 = (const float4*)(zs + ((size_t)b * Ln + l0) * Cn);
        const float4* w4  = (const float4*)onw;
        const float4* b4  = (const float4*)onb;
        float4* g4 = (float4*)(g + ((size_t)b * Ln + l0) * Cn);
        for (int e4 = t; e4 < 1536; e4 += 768) {
            int p = e4 / 24, c4 = e4 % 24;
            float4 v = *(const float4*)&yt[p * 104 + c4 * 4];
            float4 wv = w4[c4], bv = b4[c4], zv = zp4[e4];
            float m = mu[p], is = isd[p];
            float4 r;
            r.x = ((v.x - m) * is * wv.x + bv.x) * zv.x;
            r.y = ((v.y - m) * is * wv.y + bv.y) * zv.y;
            r.z = ((v.z - m) * is * wv.z + bv.z) * zv.z;
            r.w = ((v.w - m) * is * wv.w + bv.w) * zv.w;
            g4[e4] = r;
        }
    }
}

// ---------------------------------------------------------------------------
// Kernel E2: out_proj GEMM g (B,L,C) -> out (B,C,L), + scale_w.
// block = 256, tile 128 pos x 96 out, thread = 8 pos x 6 out (48 acc).
// ---------------------------------------------------------------------------
__global__ __launch_bounds__(256) void k_scan3b(
    const float* __restrict__ g, const float* __restrict__ opw,
    const float* __restrict__ scw, float* __restrict__ out)
{
    __shared__ float gls[32 * 132]; // [k][p] stride 132 (16B-aligned rows)
    __shared__ float wls[32 * 100]; // [k][o] pad 100
    const int t  = threadIdx.x;
    const int b  = blockIdx.x >> 7;
    const int l0 = (blockIdx.x & 127) << 7;
    const int tx = t & 15;          // pos tx*4+{0..3} and 64+tx*4+{0..3}
    const int ty = t >> 4;          // 6 outputs

    float acc[6][8];
#pragma unroll
    for (int i = 0; i < 6; ++i)
#pragma unroll
        for (int j = 0; j < 8; ++j) acc[i][j] = 0.f;

    const float* gbase = g + ((size_t)b * Ln + l0) * Cn;

    for (int k0 = 0; k0 < Cn; k0 += 32) {
        if (k0) __syncthreads();
        // g tile: gls[k][p] = g[(l0+p)*Cn + k0+k]
        for (int idx = t; idx < 4096; idx += 256) {
            int k = idx & 31, p = idx >> 5;
            gls[k * 132 + p] = gbase[(size_t)p * Cn + k0 + k];
        }
        for (int idx = t; idx < 3072; idx += 256) {
            int k = idx & 31, o = idx >> 5;
            wls[k * 100 + o] = opw[o * Cn + k0 + k];
        }
        __syncthreads();

#pragma unroll 4
        for (int kk = 0; kk < 32; ++kk) {
            float4 g0 = *(const float4*)&gls[kk * 132 + tx * 4];
            float4 g1 = *(const float4*)&gls[kk * 132 + 64 + tx * 4];
            const float* wr = &wls[kk * 100 + ty * 6];
            float ga[8] = {g0.x,g0.y,g0.z,g0.w,g1.x,g1.y,g1.z,g1.w};
#pragma unroll
            for (int i = 0; i < 6; ++i) {
                float w = wr[i];
#pragma unroll
                for (int jq = 0; jq < 8; ++jq)
                    acc[i][jq] = fmaf(w, ga[jq], acc[i][jq]);
            }
        }
    }

#pragma unroll
    for (int i = 0; i < 6; ++i) {
        const int o = ty * 6 + i;
        const float sc = scw[o];
        float* ob = out + ((size_t)b * Cn + o) * Ln + l0;
        float4 s0 = make_float4(acc[i][0]*sc, acc[i][1]*sc, acc[i][2]*sc, acc[i][3]*sc);
        float4 s1 = make_float4(acc[i][4]*sc, acc[i][5]*sc, acc[i][6]*sc, acc[i][7]*sc);
        *(float4*)&ob[tx * 4]      = s0;
        *(float4*)&ob[64 + tx * 4] = s1;
    }
}

// ---------------------------------------------------------------------------
extern "C" void kernel_launch(void* const* d_in, const int* in_sizes, int n_in,
                              void* d_out, int out_size, void* d_ws, size_t ws_size,
                              hipStream_t stream)
{
    const float* x     = (const float*)d_in[0];
    const float* ipw   = (const float*)d_in[1];
    const float* cw    = (const float*)d_in[2];
    const float* cb    = (const float*)d_in[3];
    const float* xpw   = (const float*)d_in[4];
    const float* dtw   = (const float*)d_in[5];
    const float* dtb   = (const float*)d_in[6];
    const float* Alogs = (const float*)d_in[7];
    const float* Ds    = (const float*)d_in[8];
    const float* onw   = (const float*)d_in[9];
    const float* onb   = (const float*)d_in[10];
    const float* opw   = (const float*)d_in[11];
    const float* scw   = (const float*)d_in[12];
    float* out = (float*)d_out;

    float* wsp = (float*)d_ws;
    size_t off = 0;
    // xc dead after k_conv -> g aliases it
    float* xc   = wsp + off;
    float* g    = wsp + off; off += (size_t)Bn * Ln * Cn;         // 6.29M
    float* zs   = wsp + off; off += (size_t)Bn * Ln * Cn;         // 6.29M
    float* u    = wsp + off; off += (size_t)Bn * Ln * Cn;         // 6.29M
    float* Pc    = wsp + off; off += (size_t)Bn * Kn * NCH * Cn;  // 0.79M
    float* Qc    = wsp + off; off += (size_t)Bn * Kn * NCH * Cn;
    float* hinit = wsp + off; off += (size_t)Bn * Kn * NCH * Cn;

    k_inproj<<<Bn * 128, 256, 0, stream>>>(x, ipw, xc, zs);
    k_conv  <<<(Bn * Ln * Cn) / 256, 256, 0, stream>>>(xc, cw, cb, u);
    k_fscan1<<<Bn * Kn * 256, 384, 0, stream>>>(u, xpw, dtw, dtb, Alogs, Pc, Qc);
    k_scan2 <<<24, 1024, 0, stream>>>(Pc, Qc, hinit);
    k_scan3a<<<Bn * 256, 768, 0, stream>>>(u, xpw, dtw, dtb, Alogs, hinit,
                                           Ds, onw, onb, zs, g);
    k_scan3b<<<Bn * 128, 256, 0, stream>>>(g, opw, scw, out);
}